// Round 12
// baseline (229.327 us; speedup 1.0000x reference)
//
#include <hip/hip_runtime.h>

#define H_ 64
#define HD_ 32
#define NP 8192
#define NR 16384
#define NC 65536
#define EP 65536
#define NCLS 11

typedef unsigned short ushort_t;
typedef unsigned int uint_t;

__device__ inline uint_t packbf2(float lo, float hi) {
    uint_t a = __builtin_bit_cast(uint_t, lo);
    uint_t b = __builtin_bit_cast(uint_t, hi);
    a = (a + 0x7FFFu + ((a >> 16) & 1u)) >> 16;
    b = (b + 0x7FFFu + ((b >> 16) & 1u)) & 0xFFFF0000u;
    return a | b;
}

// ---------------- CSR build ----------------
__global__ void k_hist(const int* __restrict__ pass_src, int* __restrict__ deg) {
    int e = blockIdx.x * 256 + threadIdx.x;
    if (e < EP) atomicAdd(&deg[pass_src[e]], 1);
}

__global__ void k_scan(const int* __restrict__ deg, int* __restrict__ off, int* __restrict__ cursor) {
    __shared__ int sums[256];
    int t = threadIdx.x;
    int local[32];
    int s = 0;
#pragma unroll
    for (int i = 0; i < 32; i++) { local[i] = s; s += deg[t * 32 + i]; }
    sums[t] = s;
    __syncthreads();
    for (int ofs = 1; ofs < 256; ofs <<= 1) {
        int u = (t >= ofs) ? sums[t - ofs] : 0;
        __syncthreads();
        sums[t] += u;
        __syncthreads();
    }
    int base = sums[t] - s;
#pragma unroll
    for (int i = 0; i < 32; i++) {
        int v = base + local[i];
        off[t * 32 + i] = v;
        cursor[t * 32 + i] = v;
    }
}

__global__ void k_scatter(const int* __restrict__ pass_src, const int* __restrict__ pass_dst,
                          const int* __restrict__ out_src, const int* __restrict__ in_dst,
                          int* __restrict__ cursor, int* __restrict__ csr_ab) {
    int e = blockIdx.x * 256 + threadIdx.x;
    if (e < EP) {
        int p = pass_src[e];
        int c = pass_dst[e];
        int a = out_src[c];
        int b = in_dst[c];
        int pos = atomicAdd(&cursor[p], 1);
        csr_ab[pos] = (a << 14) | b;
    }
}

// ---------------- permute w_mp into GEMM-friendly, LDS-bank-friendly B' ----------------
__global__ void k_perm(const float* __restrict__ w_mp, const float* __restrict__ b_mp,
                       float* __restrict__ Bp, float* __restrict__ biasp) {
    int i = blockIdx.x * 256 + threadIdx.x;  // over 64*2048
    int k = i >> 11, cg = i & 2047;
    int blk = cg >> 7, c = cg & 127;
    int quad = c >> 2, r = c & 3;
    int j = (quad < 16) ? (quad * 8 + r) : ((quad - 16) * 8 + 4 + r);
    int jp = blk * 128 + j;       // logical j' = d*64+h
    int d = jp >> 6, h = jp & 63;
    Bp[i] = w_mp[k * 2048 + h * 32 + d];
    if (i < 2048) biasp[i] = b_mp[h * 32 + d];
}

// ---------------- FeatureGen: routers -> hidden ----------------
__global__ __launch_bounds__(256) void k_router(const float* __restrict__ op,
                                                const float* __restrict__ w_op, const float* __restrict__ b_op,
                                                const float* __restrict__ w_fr, const float* __restrict__ b_fr,
                                                float* __restrict__ hidden) {
    __shared__ float s_wop[4 * 64];
    __shared__ float s_wfr[64 * 64];
    __shared__ float s_bop[64], s_bfr[64];
    __shared__ float s_tmp[16 * 64];
    int t = threadIdx.x;
    if (t < 64) { s_bop[t] = b_op[t]; s_bfr[t] = b_fr[t]; }
    if (t < 256) s_wop[t] = w_op[t];
    for (int i = t; i < 4096; i += 256) s_wfr[i] = w_fr[i];
    __syncthreads();
    int r0 = blockIdx.x * 16;
    for (int idx = t; idx < 16 * 64; idx += 256) {
        int row = idx >> 6, i = idx & 63;
        const float* o = op + (size_t)(r0 + row) * 4;
        float v = s_bop[i] + o[0] * s_wop[i] + o[1] * s_wop[64 + i] + o[2] * s_wop[128 + i] + o[3] * s_wop[192 + i];
        s_tmp[idx] = fmaxf(v, 0.f);
    }
    __syncthreads();
    for (int idx = t; idx < 16 * 64; idx += 256) {
        int row = idx >> 6, j = idx & 63;
        float acc = s_bfr[j];
        const float* tm = s_tmp + row * 64;
#pragma unroll 16
        for (int i = 0; i < 64; i++) acc += tm[i] * s_wfr[i * 64 + j];
        hidden[(size_t)(r0 + row) * 64 + j] = acc;
    }
}

// ---------------- FeatureGen: packets -> packet_feat ----------------
__global__ __launch_bounds__(256) void k_packet(const float* __restrict__ freq, const float* __restrict__ flit,
                                                const float* __restrict__ w_freq, const float* __restrict__ b_freq,
                                                const float* __restrict__ w_flit, const float* __restrict__ b_flit,
                                                const float* __restrict__ w_fp, const float* __restrict__ b_fp,
                                                float* __restrict__ pf) {
    __shared__ float s_wfl[32 * 64];
    __shared__ float s_wfp[128 * 64];
    __shared__ float s_tmp[16 * 128];
    __shared__ float s_wfq[64], s_bfq[64], s_bfl[64], s_bfp[64];
    int t = threadIdx.x;
    if (t < 64) { s_wfq[t] = w_freq[t]; s_bfq[t] = b_freq[t]; s_bfl[t] = b_flit[t]; s_bfp[t] = b_fp[t]; }
    for (int i = t; i < 2048; i += 256) s_wfl[i] = w_flit[i];
    for (int i = t; i < 8192; i += 256) s_wfp[i] = w_fp[i];
    __syncthreads();
    int r0 = blockIdx.x * 16;
    for (int idx = t; idx < 16 * 128; idx += 256) {
        int row = idx >> 7, i = idx & 127;
        float v;
        if (i < 64) {
            v = s_bfq[i] + freq[r0 + row] * s_wfq[i];
        } else {
            int ii = i - 64;
            float acc = s_bfl[ii];
            const float* f = flit + (size_t)(r0 + row) * 32;
#pragma unroll 8
            for (int k = 0; k < 32; k++) acc += f[k] * s_wfl[k * 64 + ii];
            v = acc;
        }
        s_tmp[idx] = fmaxf(v, 0.f);
    }
    __syncthreads();
    for (int idx = t; idx < 16 * 64; idx += 256) {
        int row = idx >> 6, j = idx & 63;
        float acc = s_bfp[j];
        const float* tm = s_tmp + row * 128;
#pragma unroll 16
        for (int i = 0; i < 128; i++) acc += tm[i] * s_wfp[i * 64 + j];
        pf[(size_t)(r0 + row) * 64 + j] = acc;
    }
}

// ---------------- pfeat_b[p][j'] (bf16) = pf @ B' + bias' ----------------
__global__ __launch_bounds__(256) void k_pfeat(const float* __restrict__ pf, const float* __restrict__ Bp,
                                               const float* __restrict__ biasp, ushort_t* __restrict__ pfeat_b) {
    __shared__ float As[64 * 68];
    __shared__ float Bs[64 * 132];
    int t = threadIdx.x;
    int p0 = blockIdx.x * 64;
    int j0 = blockIdx.y * 128;
#pragma unroll
    for (int it = 0; it < 4; it++) {
        int idx4 = t + it * 256;
        int r = idx4 >> 4, kq = idx4 & 15;
        float4 v = *(const float4*)(pf + (size_t)(p0 + r) * 64 + kq * 4);
        *(float4*)(As + r * 68 + kq * 4) = v;
    }
#pragma unroll
    for (int it = 0; it < 8; it++) {
        int idx4 = t + it * 256;
        int k = idx4 >> 5, c4 = idx4 & 31;
        float4 v = *(const float4*)(Bp + (size_t)k * 2048 + j0 + c4 * 4);
        *(float4*)(Bs + k * 132 + c4 * 4) = v;
    }
    __syncthreads();
    int pg = t >> 4, jg = t & 15;
    float acc0[8] = {}, acc1[8] = {}, acc2[8] = {}, acc3[8] = {};
    const float* asr = As + (pg * 4) * 68;
#pragma unroll 4
    for (int k = 0; k < 64; k++) {
        float4 w0 = *(const float4*)(Bs + k * 132 + jg * 4);
        float4 w1 = *(const float4*)(Bs + k * 132 + 64 + jg * 4);
        float a0 = asr[k], a1 = asr[68 + k], a2 = asr[136 + k], a3 = asr[204 + k];
        acc0[0] = fmaf(a0, w0.x, acc0[0]); acc0[1] = fmaf(a0, w0.y, acc0[1]);
        acc0[2] = fmaf(a0, w0.z, acc0[2]); acc0[3] = fmaf(a0, w0.w, acc0[3]);
        acc0[4] = fmaf(a0, w1.x, acc0[4]); acc0[5] = fmaf(a0, w1.y, acc0[5]);
        acc0[6] = fmaf(a0, w1.z, acc0[6]); acc0[7] = fmaf(a0, w1.w, acc0[7]);
        acc1[0] = fmaf(a1, w0.x, acc1[0]); acc1[1] = fmaf(a1, w0.y, acc1[1]);
        acc1[2] = fmaf(a1, w0.z, acc1[2]); acc1[3] = fmaf(a1, w0.w, acc1[3]);
        acc1[4] = fmaf(a1, w1.x, acc1[4]); acc1[5] = fmaf(a1, w1.y, acc1[5]);
        acc1[6] = fmaf(a1, w1.z, acc1[6]); acc1[7] = fmaf(a1, w1.w, acc1[7]);
        acc2[0] = fmaf(a2, w0.x, acc2[0]); acc2[1] = fmaf(a2, w0.y, acc2[1]);
        acc2[2] = fmaf(a2, w0.z, acc2[2]); acc2[3] = fmaf(a2, w0.w, acc2[3]);
        acc2[4] = fmaf(a2, w1.x, acc2[4]); acc2[5] = fmaf(a2, w1.y, acc2[5]);
        acc2[6] = fmaf(a2, w1.z, acc2[6]); acc2[7] = fmaf(a2, w1.w, acc2[7]);
        acc3[0] = fmaf(a3, w0.x, acc3[0]); acc3[1] = fmaf(a3, w0.y, acc3[1]);
        acc3[2] = fmaf(a3, w0.z, acc3[2]); acc3[3] = fmaf(a3, w0.w, acc3[3]);
        acc3[4] = fmaf(a3, w1.x, acc3[4]); acc3[5] = fmaf(a3, w1.y, acc3[5]);
        acc3[6] = fmaf(a3, w1.z, acc3[6]); acc3[7] = fmaf(a3, w1.w, acc3[7]);
    }
    float4 bb0 = *(const float4*)(biasp + j0 + jg * 4);
    float4 bb1 = *(const float4*)(biasp + j0 + 64 + jg * 4);
#define STORE_PP(ACC, PP) do { \
        uint4 v; \
        v.x = packbf2(ACC[0] + bb0.x, ACC[1] + bb0.y); \
        v.y = packbf2(ACC[2] + bb0.z, ACC[3] + bb0.w); \
        v.z = packbf2(ACC[4] + bb1.x, ACC[5] + bb1.y); \
        v.w = packbf2(ACC[6] + bb1.z, ACC[7] + bb1.w); \
        *(uint4*)(pfeat_b + (size_t)(p0 + pg * 4 + (PP)) * 2048 + j0 + jg * 8) = v; \
    } while (0)
    STORE_PP(acc0, 0);
    STORE_PP(acc1, 1);
    STORE_PP(acc2, 2);
    STORE_PP(acc3, 3);
#undef STORE_PP
}

// ---------------- Message passing ----------------
// wave per packet; lane = (hi,d); preg[mm] = pfeat[p][h=hi*32+mm][d] (bf16->f32).
// msplit layout [8 planes][NR][8 cols]: column c of router r lives at
// ((c>>3)*NR + r)*8 + (c&7). A 32-lane atomic burst spreads over 4 planes
// (4 L2 lines in 4 slices, 8 RMWs each) instead of serializing 32 on one line.
__global__ __launch_bounds__(256) void k_mp(const ushort_t* __restrict__ pfeat_b, const float* __restrict__ hidden,
                                            const int* __restrict__ off, const int* __restrict__ deg,
                                            const int* __restrict__ csr_ab, float* __restrict__ msplit) {
    int wid = __builtin_amdgcn_readfirstlane((blockIdx.x << 2) + (threadIdx.x >> 6));
    int lane = threadIdx.x & 63;
    int hi = lane >> 5, d = lane & 31;
    const uint4* pr = (const uint4*)(pfeat_b + (size_t)wid * 2048 + d * 64 + hi * 32);
    float preg[32];
#pragma unroll
    for (int q = 0; q < 4; q++) {
        uint4 u = pr[q];
        preg[q * 8 + 0] = __builtin_bit_cast(float, u.x << 16);
        preg[q * 8 + 1] = __builtin_bit_cast(float, u.x & 0xFFFF0000u);
        preg[q * 8 + 2] = __builtin_bit_cast(float, u.y << 16);
        preg[q * 8 + 3] = __builtin_bit_cast(float, u.y & 0xFFFF0000u);
        preg[q * 8 + 4] = __builtin_bit_cast(float, u.z << 16);
        preg[q * 8 + 5] = __builtin_bit_cast(float, u.z & 0xFFFF0000u);
        preg[q * 8 + 6] = __builtin_bit_cast(float, u.w << 16);
        preg[q * 8 + 7] = __builtin_bit_cast(float, u.w & 0xFFFF0000u);
    }
    int e0 = off[wid];
    int n = deg[wid];
    if (n <= 0) return;
    const float4* hb4 = (const float4*)hidden;
    // per-lane plane bases (constant): vin -> plane d>>3, vout -> plane 4+(d>>3)
    size_t base_in  = ((size_t)(d >> 3) * NR) * 8 + (d & 7);
    size_t base_out = ((size_t)(4 + (d >> 3)) * NR) * 8 + (d & 7);

#define LOADX(XA, XB, PK) do { \
        int a_ = (PK) >> 14, b_ = (PK) & 16383; \
        const float4* qa_ = hb4 + a_ * 16 + hi * 8; \
        const float4* qb_ = hb4 + b_ * 16 + hi * 8; \
        _Pragma("unroll") for (int q = 0; q < 8; q++) XA[q] = qa_[q]; \
        _Pragma("unroll") for (int q = 0; q < 8; q++) XB[q] = qb_[q]; \
    } while (0)

#define COMPUTE(XA, XB, PK) do { \
        int a_ = (PK) >> 14, b_ = (PK) & 16383; \
        float vi0 = 0, vi1 = 0, vi2 = 0, vi3 = 0, vo0 = 0, vo1 = 0, vo2 = 0, vo3 = 0; \
        _Pragma("unroll") for (int q = 0; q < 8; q++) { \
            vi0 = fmaf(preg[4 * q + 0], XA[q].x, vi0); \
            vi1 = fmaf(preg[4 * q + 1], XA[q].y, vi1); \
            vi2 = fmaf(preg[4 * q + 2], XA[q].z, vi2); \
            vi3 = fmaf(preg[4 * q + 3], XA[q].w, vi3); \
            vo0 = fmaf(preg[4 * q + 0], XB[q].x, vo0); \
            vo1 = fmaf(preg[4 * q + 1], XB[q].y, vo1); \
            vo2 = fmaf(preg[4 * q + 2], XB[q].z, vo2); \
            vo3 = fmaf(preg[4 * q + 3], XB[q].w, vo3); \
        } \
        float vin = (vi0 + vi1) + (vi2 + vi3); \
        float vout = (vo0 + vo1) + (vo2 + vo3); \
        vin += __shfl_xor(vin, 32); \
        vout += __shfl_xor(vout, 32); \
        if (hi == 0) atomicAdd(&msplit[base_in + (size_t)b_ * 8], vin); \
        else         atomicAdd(&msplit[base_out + (size_t)a_ * 8], vout); \
    } while (0)

    float4 xa0[8], xb0[8], xa1[8], xb1[8];
    int pk0 = csr_ab[e0];
    LOADX(xa0, xb0, pk0);
    int pk1 = 0;
    if (n > 1) { pk1 = csr_ab[e0 + 1]; LOADX(xa1, xb1, pk1); }
    int i = 0;
    while (true) {
        COMPUTE(xa0, xb0, pk0);
        if (i + 2 < n) { pk0 = csr_ab[e0 + i + 2]; LOADX(xa0, xb0, pk0); }
        if (i + 1 >= n) break;
        COMPUTE(xa1, xb1, pk1);
        if (i + 3 < n) { pk1 = csr_ab[e0 + i + 3]; LOADX(xa1, xb1, pk1); }
        if (i + 2 >= n) break;
        i += 2;
    }
#undef LOADX
#undef COMPUTE
}

// ---------------- update: hidden = relu(hidden + m^T-planes) ----------------
// Non-final: streaming, re-zeroes msplit. Thread i handles float4 (r=i>>4, c0=(i&15)*4);
// the float4 lies within plane c0>>3 at ((c0>>3)*NR + r)*8 + (c0&7) (16B aligned).
__global__ __launch_bounds__(256) void k_update0(float* __restrict__ hidden, float* __restrict__ msplit) {
    int i = blockIdx.x * 256 + threadIdx.x;  // exactly NR*16 threads
    int r = i >> 4;
    int c0 = (i & 15) * 4;
    size_t moff = ((size_t)(c0 >> 3) * NR + r) * 8 + (c0 & 7);
    float4 mv = *(const float4*)(msplit + moff);
    float4* h4 = (float4*)hidden;
    float4 hv = h4[i];
    float4 v;
    v.x = fmaxf(hv.x + mv.x, 0.f);
    v.y = fmaxf(hv.y + mv.y, 0.f);
    v.z = fmaxf(hv.z + mv.z, 0.f);
    v.w = fmaxf(hv.w + mv.w, 0.f);
    h4[i] = v;
    *(float4*)(msplit + moff) = make_float4(0.f, 0.f, 0.f, 0.f);
}

// Final: no hidden store; fused column-sum pooling into line-padded embed.
// Grid 128. Thread's float4 covers columns c0..c0+3 with c0 = (t&15)*4 (loop-invariant).
__global__ __launch_bounds__(256) void k_update1(const float* __restrict__ hidden, const float* __restrict__ msplit,
                                                 float* __restrict__ embed) {
    int t = threadIdx.x;
    int base = blockIdx.x * 256 + t;
    const float4* h4 = (const float4*)hidden;
    int c0 = (base & 15) * 4;
    size_t pbase = ((size_t)(c0 >> 3) * NR) * 8 + (c0 & 7);
    float col[4] = {0.f, 0.f, 0.f, 0.f};
    for (int i = base; i < NR * 16; i += 128 * 256) {
        int r = i >> 4;
        float4 hv = h4[i];
        float4 mv = *(const float4*)(msplit + pbase + (size_t)r * 8);
        col[0] += fmaxf(hv.x + mv.x, 0.f);
        col[1] += fmaxf(hv.y + mv.y, 0.f);
        col[2] += fmaxf(hv.z + mv.z, 0.f);
        col[3] += fmaxf(hv.w + mv.w, 0.f);
    }
#pragma unroll
    for (int k = 0; k < 4; k++) {
        col[k] += __shfl_xor(col[k], 16);
        col[k] += __shfl_xor(col[k], 32);
    }
    __shared__ float scol[4][64];
    int w = t >> 6, lane = t & 63;
    if (lane < 16) {
#pragma unroll
        for (int k = 0; k < 4; k++) scol[w][lane * 4 + k] = col[k];
    }
    __syncthreads();
    if (t < 64) {
        atomicAdd(&embed[t * 16], scol[0][t] + scol[1][t] + scol[2][t] + scol[3][t]);
    }
}

// ---------------- prediction head (embed is line-padded: stride 16 floats) ----------------
__global__ void k_head(const float* __restrict__ embed,
                       const float* __restrict__ w_h1, const float* __restrict__ b_h1,
                       const float* __restrict__ w_h2, const float* __restrict__ b_h2,
                       const float* __restrict__ w_out, const float* __restrict__ b_out,
                       float* __restrict__ out) {
    __shared__ float e1[64], e2[64];
    int t = threadIdx.x;
    float acc = b_h1[t];
#pragma unroll 16
    for (int k = 0; k < 64; k++) acc += embed[k * 16] * w_h1[k * 64 + t];
    e1[t] = fmaxf(acc, 0.f);
    __syncthreads();
    acc = b_h2[t];
#pragma unroll 16
    for (int k = 0; k < 64; k++) acc += e1[k] * w_h2[k * 64 + t];
    e2[t] = fmaxf(acc, 0.f);
    __syncthreads();
    if (t < NCLS) {
        acc = b_out[t];
#pragma unroll 16
        for (int k = 0; k < 64; k++) acc += e2[k] * w_out[k * NCLS + t];
        out[t] = acc;
    }
}

extern "C" void kernel_launch(void* const* d_in, const int* in_sizes, int n_in,
                              void* d_out, int out_size, void* d_ws, size_t ws_size,
                              hipStream_t stream) {
    const float* freq   = (const float*)d_in[0];
    const float* flit   = (const float*)d_in[1];
    const float* op     = (const float*)d_in[2];
    const int* out_src  = (const int*)d_in[4];
    const int* in_dst   = (const int*)d_in[7];
    const int* pass_src = (const int*)d_in[8];
    const int* pass_dst = (const int*)d_in[9];
    const float* w_freq = (const float*)d_in[10];
    const float* b_freq = (const float*)d_in[11];
    const float* w_flit = (const float*)d_in[12];
    const float* b_flit = (const float*)d_in[13];
    const float* w_op   = (const float*)d_in[14];
    const float* b_op   = (const float*)d_in[15];
    const float* w_fp   = (const float*)d_in[18];
    const float* b_fp   = (const float*)d_in[19];
    const float* w_fr   = (const float*)d_in[20];
    const float* b_fr   = (const float*)d_in[21];
    const float* w_mp   = (const float*)d_in[24];
    const float* b_mp   = (const float*)d_in[25];
    const float* w_h1   = (const float*)d_in[26];
    const float* b_h1   = (const float*)d_in[27];
    const float* w_h2   = (const float*)d_in[28];
    const float* b_h2   = (const float*)d_in[29];
    const float* w_out  = (const float*)d_in[30];
    const float* b_out  = (const float*)d_in[31];
    float* out = (float*)d_out;

    char* ws = (char*)d_ws;
    ushort_t* pfeat_b  = (ushort_t*)(ws);                  // 32 MB
    float* hidden      = (float*)(ws + 33554432);          // 4 MB
    float* msplit      = (float*)(ws + 37748736);          // 4 MB ([8][NR][8] planes)
    float* embed       = (float*)(ws + 41943040);          // 4 KB (padded: 64 x 16 floats)
    float* packet_feat = (float*)(ws + 41947136);          // 2 MB
    float* Bp          = (float*)(ws + 44044288);          // 512 KB
    float* biasp       = (float*)(ws + 44568576);          // 8 KB
    int*   deg         = (int*)  (ws + 44576768);          // 32 KB
    int*   off         = (int*)  (ws + 44609536);          // 32 KB
    int*   cursor      = (int*)  (ws + 44642304);          // 32 KB
    int*   csr_ab      = (int*)  (ws + 44675072);          // 256 KB

    // CSR build
    hipMemsetAsync(deg, 0, NP * sizeof(int), stream);
    k_hist<<<EP / 256, 256, 0, stream>>>(pass_src, deg);
    k_scan<<<1, 256, 0, stream>>>(deg, off, cursor);
    k_scatter<<<EP / 256, 256, 0, stream>>>(pass_src, pass_dst, out_src, in_dst, cursor, csr_ab);

    // Weight permutation + features
    k_perm<<<512, 256, 0, stream>>>(w_mp, b_mp, Bp, biasp);
    k_packet<<<NP / 16, 256, 0, stream>>>(freq, flit, w_freq, b_freq, w_flit, b_flit, w_fp, b_fp, packet_feat);
    k_pfeat<<<dim3(NP / 64, 16), 256, 0, stream>>>(packet_feat, Bp, biasp, pfeat_b);
    k_router<<<NR / 16, 256, 0, stream>>>(op, w_op, b_op, w_fr, b_fr, hidden);

    // MP iteration 0 (k_update0 re-zeroes msplit for iteration 1)
    hipMemsetAsync(msplit, 0, NR * 64 * sizeof(float) + 4096, stream);  // msplit + padded embed
    k_mp<<<NP / 4, 256, 0, stream>>>(pfeat_b, hidden, off, deg, csr_ab, msplit);
    k_update0<<<NR * 16 / 256, 256, 0, stream>>>(hidden, msplit);

    // MP iteration 1 (final: fused pooling, no hidden store)
    k_mp<<<NP / 4, 256, 0, stream>>>(pfeat_b, hidden, off, deg, csr_ab, msplit);
    k_update1<<<128, 256, 0, stream>>>(hidden, msplit, embed);

    // Head
    k_head<<<1, 64, 0, stream>>>(embed, w_h1, b_h1, w_h2, b_h2, w_out, b_out, out);
}

// Round 13
// 155.018 us; speedup vs baseline: 1.4794x; 1.4794x over previous
//
#include <hip/hip_runtime.h>

#define H_ 64
#define HD_ 32
#define NP 8192
#define NR 16384
#define NC 65536
#define EP 65536
#define NCLS 11

typedef unsigned short ushort_t;
typedef unsigned int uint_t;

__device__ inline uint_t packbf2(float lo, float hi) {
    uint_t a = __builtin_bit_cast(uint_t, lo);
    uint_t b = __builtin_bit_cast(uint_t, hi);
    a = (a + 0x7FFFu + ((a >> 16) & 1u)) >> 16;
    b = (b + 0x7FFFu + ((b >> 16) & 1u)) & 0xFFFF0000u;
    return a | b;
}

// ---------------- CSR build ----------------
__global__ void k_hist(const int* __restrict__ pass_src, int* __restrict__ deg) {
    int e = blockIdx.x * 256 + threadIdx.x;
    if (e < EP) atomicAdd(&deg[pass_src[e]], 1);
}

__global__ void k_scan(const int* __restrict__ deg, int* __restrict__ off, int* __restrict__ cursor) {
    __shared__ int sums[256];
    int t = threadIdx.x;
    int local[32];
    int s = 0;
#pragma unroll
    for (int i = 0; i < 32; i++) { local[i] = s; s += deg[t * 32 + i]; }
    sums[t] = s;
    __syncthreads();
    for (int ofs = 1; ofs < 256; ofs <<= 1) {
        int u = (t >= ofs) ? sums[t - ofs] : 0;
        __syncthreads();
        sums[t] += u;
        __syncthreads();
    }
    int base = sums[t] - s;
#pragma unroll
    for (int i = 0; i < 32; i++) {
        int v = base + local[i];
        off[t * 32 + i] = v;
        cursor[t * 32 + i] = v;
    }
}

__global__ void k_scatter(const int* __restrict__ pass_src, const int* __restrict__ pass_dst,
                          const int* __restrict__ out_src, const int* __restrict__ in_dst,
                          int* __restrict__ cursor, int* __restrict__ csr_ab) {
    int e = blockIdx.x * 256 + threadIdx.x;
    if (e < EP) {
        int p = pass_src[e];
        int c = pass_dst[e];
        int a = out_src[c];
        int b = in_dst[c];
        int pos = atomicAdd(&cursor[p], 1);
        csr_ab[pos] = (a << 14) | b;
    }
}

// ---------------- permute w_mp into GEMM-friendly, LDS-bank-friendly B' ----------------
__global__ void k_perm(const float* __restrict__ w_mp, const float* __restrict__ b_mp,
                       float* __restrict__ Bp, float* __restrict__ biasp) {
    int i = blockIdx.x * 256 + threadIdx.x;  // over 64*2048
    int k = i >> 11, cg = i & 2047;
    int blk = cg >> 7, c = cg & 127;
    int quad = c >> 2, r = c & 3;
    int j = (quad < 16) ? (quad * 8 + r) : ((quad - 16) * 8 + 4 + r);
    int jp = blk * 128 + j;       // logical j' = d*64+h
    int d = jp >> 6, h = jp & 63;
    Bp[i] = w_mp[k * 2048 + h * 32 + d];
    if (i < 2048) biasp[i] = b_mp[h * 32 + d];
}

// ---------------- FeatureGen: routers -> hidden ----------------
__global__ __launch_bounds__(256) void k_router(const float* __restrict__ op,
                                                const float* __restrict__ w_op, const float* __restrict__ b_op,
                                                const float* __restrict__ w_fr, const float* __restrict__ b_fr,
                                                float* __restrict__ hidden) {
    __shared__ float s_wop[4 * 64];
    __shared__ float s_wfr[64 * 64];
    __shared__ float s_bop[64], s_bfr[64];
    __shared__ float s_tmp[16 * 64];
    int t = threadIdx.x;
    if (t < 64) { s_bop[t] = b_op[t]; s_bfr[t] = b_fr[t]; }
    if (t < 256) s_wop[t] = w_op[t];
    for (int i = t; i < 4096; i += 256) s_wfr[i] = w_fr[i];
    __syncthreads();
    int r0 = blockIdx.x * 16;
    for (int idx = t; idx < 16 * 64; idx += 256) {
        int row = idx >> 6, i = idx & 63;
        const float* o = op + (size_t)(r0 + row) * 4;
        float v = s_bop[i] + o[0] * s_wop[i] + o[1] * s_wop[64 + i] + o[2] * s_wop[128 + i] + o[3] * s_wop[192 + i];
        s_tmp[idx] = fmaxf(v, 0.f);
    }
    __syncthreads();
    for (int idx = t; idx < 16 * 64; idx += 256) {
        int row = idx >> 6, j = idx & 63;
        float acc = s_bfr[j];
        const float* tm = s_tmp + row * 64;
#pragma unroll 16
        for (int i = 0; i < 64; i++) acc += tm[i] * s_wfr[i * 64 + j];
        hidden[(size_t)(r0 + row) * 64 + j] = acc;
    }
}

// ---------------- FeatureGen: packets -> packet_feat ----------------
__global__ __launch_bounds__(256) void k_packet(const float* __restrict__ freq, const float* __restrict__ flit,
                                                const float* __restrict__ w_freq, const float* __restrict__ b_freq,
                                                const float* __restrict__ w_flit, const float* __restrict__ b_flit,
                                                const float* __restrict__ w_fp, const float* __restrict__ b_fp,
                                                float* __restrict__ pf) {
    __shared__ float s_wfl[32 * 64];
    __shared__ float s_wfp[128 * 64];
    __shared__ float s_tmp[16 * 128];
    __shared__ float s_wfq[64], s_bfq[64], s_bfl[64], s_bfp[64];
    int t = threadIdx.x;
    if (t < 64) { s_wfq[t] = w_freq[t]; s_bfq[t] = b_freq[t]; s_bfl[t] = b_flit[t]; s_bfp[t] = b_fp[t]; }
    for (int i = t; i < 2048; i += 256) s_wfl[i] = w_flit[i];
    for (int i = t; i < 8192; i += 256) s_wfp[i] = w_fp[i];
    __syncthreads();
    int r0 = blockIdx.x * 16;
    for (int idx = t; idx < 16 * 128; idx += 256) {
        int row = idx >> 7, i = idx & 127;
        float v;
        if (i < 64) {
            v = s_bfq[i] + freq[r0 + row] * s_wfq[i];
        } else {
            int ii = i - 64;
            float acc = s_bfl[ii];
            const float* f = flit + (size_t)(r0 + row) * 32;
#pragma unroll 8
            for (int k = 0; k < 32; k++) acc += f[k] * s_wfl[k * 64 + ii];
            v = acc;
        }
        s_tmp[idx] = fmaxf(v, 0.f);
    }
    __syncthreads();
    for (int idx = t; idx < 16 * 64; idx += 256) {
        int row = idx >> 6, j = idx & 63;
        float acc = s_bfp[j];
        const float* tm = s_tmp + row * 128;
#pragma unroll 16
        for (int i = 0; i < 128; i++) acc += tm[i] * s_wfp[i * 64 + j];
        pf[(size_t)(r0 + row) * 64 + j] = acc;
    }
}

// ---------------- pfeat_b[p][j'] (bf16) = pf @ B' + bias' ----------------
__global__ __launch_bounds__(256) void k_pfeat(const float* __restrict__ pf, const float* __restrict__ Bp,
                                               const float* __restrict__ biasp, ushort_t* __restrict__ pfeat_b) {
    __shared__ float As[64 * 68];
    __shared__ float Bs[64 * 132];
    int t = threadIdx.x;
    int p0 = blockIdx.x * 64;
    int j0 = blockIdx.y * 128;
#pragma unroll
    for (int it = 0; it < 4; it++) {
        int idx4 = t + it * 256;
        int r = idx4 >> 4, kq = idx4 & 15;
        float4 v = *(const float4*)(pf + (size_t)(p0 + r) * 64 + kq * 4);
        *(float4*)(As + r * 68 + kq * 4) = v;
    }
#pragma unroll
    for (int it = 0; it < 8; it++) {
        int idx4 = t + it * 256;
        int k = idx4 >> 5, c4 = idx4 & 31;
        float4 v = *(const float4*)(Bp + (size_t)k * 2048 + j0 + c4 * 4);
        *(float4*)(Bs + k * 132 + c4 * 4) = v;
    }
    __syncthreads();
    int pg = t >> 4, jg = t & 15;
    float acc0[8] = {}, acc1[8] = {}, acc2[8] = {}, acc3[8] = {};
    const float* asr = As + (pg * 4) * 68;
#pragma unroll 4
    for (int k = 0; k < 64; k++) {
        float4 w0 = *(const float4*)(Bs + k * 132 + jg * 4);
        float4 w1 = *(const float4*)(Bs + k * 132 + 64 + jg * 4);
        float a0 = asr[k], a1 = asr[68 + k], a2 = asr[136 + k], a3 = asr[204 + k];
        acc0[0] = fmaf(a0, w0.x, acc0[0]); acc0[1] = fmaf(a0, w0.y, acc0[1]);
        acc0[2] = fmaf(a0, w0.z, acc0[2]); acc0[3] = fmaf(a0, w0.w, acc0[3]);
        acc0[4] = fmaf(a0, w1.x, acc0[4]); acc0[5] = fmaf(a0, w1.y, acc0[5]);
        acc0[6] = fmaf(a0, w1.z, acc0[6]); acc0[7] = fmaf(a0, w1.w, acc0[7]);
        acc1[0] = fmaf(a1, w0.x, acc1[0]); acc1[1] = fmaf(a1, w0.y, acc1[1]);
        acc1[2] = fmaf(a1, w0.z, acc1[2]); acc1[3] = fmaf(a1, w0.w, acc1[3]);
        acc1[4] = fmaf(a1, w1.x, acc1[4]); acc1[5] = fmaf(a1, w1.y, acc1[5]);
        acc1[6] = fmaf(a1, w1.z, acc1[6]); acc1[7] = fmaf(a1, w1.w, acc1[7]);
        acc2[0] = fmaf(a2, w0.x, acc2[0]); acc2[1] = fmaf(a2, w0.y, acc2[1]);
        acc2[2] = fmaf(a2, w0.z, acc2[2]); acc2[3] = fmaf(a2, w0.w, acc2[3]);
        acc2[4] = fmaf(a2, w1.x, acc2[4]); acc2[5] = fmaf(a2, w1.y, acc2[5]);
        acc2[6] = fmaf(a2, w1.z, acc2[6]); acc2[7] = fmaf(a2, w1.w, acc2[7]);
        acc3[0] = fmaf(a3, w0.x, acc3[0]); acc3[1] = fmaf(a3, w0.y, acc3[1]);
        acc3[2] = fmaf(a3, w0.z, acc3[2]); acc3[3] = fmaf(a3, w0.w, acc3[3]);
        acc3[4] = fmaf(a3, w1.x, acc3[4]); acc3[5] = fmaf(a3, w1.y, acc3[5]);
        acc3[6] = fmaf(a3, w1.z, acc3[6]); acc3[7] = fmaf(a3, w1.w, acc3[7]);
    }
    float4 bb0 = *(const float4*)(biasp + j0 + jg * 4);
    float4 bb1 = *(const float4*)(biasp + j0 + 64 + jg * 4);
#define STORE_PP(ACC, PP) do { \
        uint4 v; \
        v.x = packbf2(ACC[0] + bb0.x, ACC[1] + bb0.y); \
        v.y = packbf2(ACC[2] + bb0.z, ACC[3] + bb0.w); \
        v.z = packbf2(ACC[4] + bb1.x, ACC[5] + bb1.y); \
        v.w = packbf2(ACC[6] + bb1.z, ACC[7] + bb1.w); \
        *(uint4*)(pfeat_b + (size_t)(p0 + pg * 4 + (PP)) * 2048 + j0 + jg * 8) = v; \
    } while (0)
    STORE_PP(acc0, 0);
    STORE_PP(acc1, 1);
    STORE_PP(acc2, 2);
    STORE_PP(acc3, 3);
#undef STORE_PP
}

// ---------------- Message passing (LDS-staged, group-of-4 pipelined) ----------------
// wave per packet; lane = (hi,d); preg[mm] = pfeat[p][h=hi*32+mm][d] (bf16->f32).
// Per group of 4 edges: 8 hidden rows fetched coalescedly (lane -> row piece,
// 2 independent float4 loads/lane = ONE memory round trip for 8 rows), staged in
// per-wave LDS, consumed as broadcast ds_reads. Next group's loads are issued
// before this group's compute -> latency hidden under ~600cy of FMA/ds_read.
__global__ __launch_bounds__(256) void k_mp(const ushort_t* __restrict__ pfeat_b, const float* __restrict__ hidden,
                                            const int* __restrict__ off, const int* __restrict__ deg,
                                            const int* __restrict__ csr_ab, float* __restrict__ m) {
    __shared__ float lds[4][8][64];   // per-wave 8 rows x 64 floats (8KB total)
    int wv = threadIdx.x >> 6;
    int wid = __builtin_amdgcn_readfirstlane((blockIdx.x << 2) + wv);
    int lane = threadIdx.x & 63;
    int hi = lane >> 5, d = lane & 31;
    const uint4* pr = (const uint4*)(pfeat_b + (size_t)wid * 2048 + d * 64 + hi * 32);
    float preg[32];
#pragma unroll
    for (int q = 0; q < 4; q++) {
        uint4 u = pr[q];
        preg[q * 8 + 0] = __builtin_bit_cast(float, u.x << 16);
        preg[q * 8 + 1] = __builtin_bit_cast(float, u.x & 0xFFFF0000u);
        preg[q * 8 + 2] = __builtin_bit_cast(float, u.y << 16);
        preg[q * 8 + 3] = __builtin_bit_cast(float, u.y & 0xFFFF0000u);
        preg[q * 8 + 4] = __builtin_bit_cast(float, u.z << 16);
        preg[q * 8 + 5] = __builtin_bit_cast(float, u.z & 0xFFFF0000u);
        preg[q * 8 + 6] = __builtin_bit_cast(float, u.w << 16);
        preg[q * 8 + 7] = __builtin_bit_cast(float, u.w & 0xFFFF0000u);
    }
    int e0 = off[wid];
    int n = deg[wid];
    if (n <= 0) return;
    const float4* hb4 = (const float4*)hidden;

    // staging roles (constant per lane)
    int ridx = lane >> 3;      // 0..7: row slot = edge (ridx>>1), a/b = ridx&1
    int jj = ridx >> 1;        // edge-in-group this lane stages
    int ab = ridx & 1;
    int qq = lane & 7;         // float4 piece within row (qq and qq+8)
    int elast = e0 + n - 1;

    float4 v0, v1;
    int pkj;
    // prologue: load group 0
    {
        int ec = e0 + jj; if (ec > elast) ec = elast;
        pkj = csr_ab[ec];
        int row = ab ? (pkj & 16383) : (pkj >> 14);
        v0 = hb4[row * 16 + qq];
        v1 = hb4[row * 16 + 8 + qq];
    }
    int ngroups = (n + 3) >> 2;
    for (int g = 0; g < ngroups; ++g) {
        // stage group g into LDS
        *(float4*)&lds[wv][ridx][qq * 4] = v0;
        *(float4*)&lds[wv][ridx][qq * 4 + 32] = v1;
        int pkcur = pkj;
        // issue group g+1 loads (in flight across compute of g)
        if (g + 1 < ngroups) {
            int ec = e0 + (g + 1) * 4 + jj; if (ec > elast) ec = elast;
            pkj = csr_ab[ec];
            int row = ab ? (pkj & 16383) : (pkj >> 14);
            v0 = hb4[row * 16 + qq];
            v1 = hb4[row * 16 + 8 + qq];
        }
        int i0 = g * 4;
#pragma unroll
        for (int j = 0; j < 4; ++j) {
            if (i0 + j < n) {
                int pke = __shfl(pkcur, 16 * j, 64);   // lane 16j holds edge j's pk
                int a_ = pke >> 14, b_ = pke & 16383;
                const float* ha = &lds[wv][2 * j][hi * 32];
                const float* hb = &lds[wv][2 * j + 1][hi * 32];
                float vi0 = 0, vi1 = 0, vi2 = 0, vi3 = 0, vo0 = 0, vo1 = 0, vo2 = 0, vo3 = 0;
#pragma unroll
                for (int q = 0; q < 8; q++) {
                    float4 xa = *(const float4*)(ha + q * 4);
                    float4 xb = *(const float4*)(hb + q * 4);
                    vi0 = fmaf(preg[4 * q + 0], xa.x, vi0);
                    vi1 = fmaf(preg[4 * q + 1], xa.y, vi1);
                    vi2 = fmaf(preg[4 * q + 2], xa.z, vi2);
                    vi3 = fmaf(preg[4 * q + 3], xa.w, vi3);
                    vo0 = fmaf(preg[4 * q + 0], xb.x, vo0);
                    vo1 = fmaf(preg[4 * q + 1], xb.y, vo1);
                    vo2 = fmaf(preg[4 * q + 2], xb.z, vo2);
                    vo3 = fmaf(preg[4 * q + 3], xb.w, vo3);
                }
                float vin = (vi0 + vi1) + (vi2 + vi3);
                float vout = (vo0 + vo1) + (vo2 + vo3);
                vin += __shfl_xor(vin, 32);
                vout += __shfl_xor(vout, 32);
                if (hi == 0) atomicAdd(&m[(size_t)b_ * 64 + d], vin);
                else         atomicAdd(&m[(size_t)a_ * 64 + 32 + d], vout);
            }
        }
    }
}

// ---------------- update: hidden = relu(hidden + m) ----------------
// Non-final: streaming, also re-zeroes m. Grid 1024 (one float4/thread).
__global__ __launch_bounds__(256) void k_update0(float* __restrict__ hidden, float* __restrict__ m) {
    int i = blockIdx.x * 256 + threadIdx.x;  // exactly NR*16 threads
    float4* h4 = (float4*)hidden;
    float4* m4 = (float4*)m;
    float4 hv = h4[i];
    float4 mv = m4[i];
    float4 v;
    v.x = fmaxf(hv.x + mv.x, 0.f);
    v.y = fmaxf(hv.y + mv.y, 0.f);
    v.z = fmaxf(hv.z + mv.z, 0.f);
    v.w = fmaxf(hv.w + mv.w, 0.f);
    h4[i] = v;
    m4[i] = make_float4(0.f, 0.f, 0.f, 0.f);
}

// Final: hidden never read again -> no store; fused column-sum pooling into
// line-padded embed (embed[c*16], 64B apart -> atomics hit distinct L2 lines).
__global__ __launch_bounds__(256) void k_update1(const float* __restrict__ hidden, const float* __restrict__ m,
                                                 float* __restrict__ embed) {
    int t = threadIdx.x;
    int base = blockIdx.x * 256 + t;
    const float4* h4 = (const float4*)hidden;
    const float4* m4 = (const float4*)m;
    float col[4] = {0.f, 0.f, 0.f, 0.f};
    for (int i = base; i < NR * 16; i += 128 * 256) {
        float4 hv = h4[i];
        float4 mv = m4[i];
        col[0] += fmaxf(hv.x + mv.x, 0.f);
        col[1] += fmaxf(hv.y + mv.y, 0.f);
        col[2] += fmaxf(hv.z + mv.z, 0.f);
        col[3] += fmaxf(hv.w + mv.w, 0.f);
    }
#pragma unroll
    for (int k = 0; k < 4; k++) {
        col[k] += __shfl_xor(col[k], 16);
        col[k] += __shfl_xor(col[k], 32);
    }
    __shared__ float scol[4][64];
    int w = t >> 6, lane = t & 63;
    if (lane < 16) {
#pragma unroll
        for (int k = 0; k < 4; k++) scol[w][lane * 4 + k] = col[k];
    }
    __syncthreads();
    if (t < 64) {
        atomicAdd(&embed[t * 16], scol[0][t] + scol[1][t] + scol[2][t] + scol[3][t]);
    }
}

// ---------------- prediction head (embed is line-padded: stride 16 floats) ----------------
__global__ void k_head(const float* __restrict__ embed,
                       const float* __restrict__ w_h1, const float* __restrict__ b_h1,
                       const float* __restrict__ w_h2, const float* __restrict__ b_h2,
                       const float* __restrict__ w_out, const float* __restrict__ b_out,
                       float* __restrict__ out) {
    __shared__ float e1[64], e2[64];
    int t = threadIdx.x;
    float acc = b_h1[t];
#pragma unroll 16
    for (int k = 0; k < 64; k++) acc += embed[k * 16] * w_h1[k * 64 + t];
    e1[t] = fmaxf(acc, 0.f);
    __syncthreads();
    acc = b_h2[t];
#pragma unroll 16
    for (int k = 0; k < 64; k++) acc += e1[k] * w_h2[k * 64 + t];
    e2[t] = fmaxf(acc, 0.f);
    __syncthreads();
    if (t < NCLS) {
        acc = b_out[t];
#pragma unroll 16
        for (int k = 0; k < 64; k++) acc += e2[k] * w_out[k * NCLS + t];
        out[t] = acc;
    }
}

extern "C" void kernel_launch(void* const* d_in, const int* in_sizes, int n_in,
                              void* d_out, int out_size, void* d_ws, size_t ws_size,
                              hipStream_t stream) {
    const float* freq   = (const float*)d_in[0];
    const float* flit   = (const float*)d_in[1];
    const float* op     = (const float*)d_in[2];
    const int* out_src  = (const int*)d_in[4];
    const int* in_dst   = (const int*)d_in[7];
    const int* pass_src = (const int*)d_in[8];
    const int* pass_dst = (const int*)d_in[9];
    const float* w_freq = (const float*)d_in[10];
    const float* b_freq = (const float*)d_in[11];
    const float* w_flit = (const float*)d_in[12];
    const float* b_flit = (const float*)d_in[13];
    const float* w_op   = (const float*)d_in[14];
    const float* b_op   = (const float*)d_in[15];
    const float* w_fp   = (const float*)d_in[18];
    const float* b_fp   = (const float*)d_in[19];
    const float* w_fr   = (const float*)d_in[20];
    const float* b_fr   = (const float*)d_in[21];
    const float* w_mp   = (const float*)d_in[24];
    const float* b_mp   = (const float*)d_in[25];
    const float* w_h1   = (const float*)d_in[26];
    const float* b_h1   = (const float*)d_in[27];
    const float* w_h2   = (const float*)d_in[28];
    const float* b_h2   = (const float*)d_in[29];
    const float* w_out  = (const float*)d_in[30];
    const float* b_out  = (const float*)d_in[31];
    float* out = (float*)d_out;

    char* ws = (char*)d_ws;
    ushort_t* pfeat_b  = (ushort_t*)(ws);                  // 32 MB
    float* hidden      = (float*)(ws + 33554432);          // 4 MB
    float* m           = (float*)(ws + 37748736);          // 4 MB
    float* embed       = (float*)(ws + 41943040);          // 4 KB (padded: 64 x 16 floats)
    float* packet_feat = (float*)(ws + 41947136);          // 2 MB
    float* Bp          = (float*)(ws + 44044288);          // 512 KB
    float* biasp       = (float*)(ws + 44568576);          // 8 KB
    int*   deg         = (int*)  (ws + 44576768);          // 32 KB
    int*   off         = (int*)  (ws + 44609536);          // 32 KB
    int*   cursor      = (int*)  (ws + 44642304);          // 32 KB
    int*   csr_ab      = (int*)  (ws + 44675072);          // 256 KB

    // CSR build
    hipMemsetAsync(deg, 0, NP * sizeof(int), stream);
    k_hist<<<EP / 256, 256, 0, stream>>>(pass_src, deg);
    k_scan<<<1, 256, 0, stream>>>(deg, off, cursor);
    k_scatter<<<EP / 256, 256, 0, stream>>>(pass_src, pass_dst, out_src, in_dst, cursor, csr_ab);

    // Weight permutation + features
    k_perm<<<512, 256, 0, stream>>>(w_mp, b_mp, Bp, biasp);
    k_packet<<<NP / 16, 256, 0, stream>>>(freq, flit, w_freq, b_freq, w_flit, b_flit, w_fp, b_fp, packet_feat);
    k_pfeat<<<dim3(NP / 64, 16), 256, 0, stream>>>(packet_feat, Bp, biasp, pfeat_b);
    k_router<<<NR / 16, 256, 0, stream>>>(op, w_op, b_op, w_fr, b_fr, hidden);

    // MP iteration 0 (k_update0 re-zeroes m for iteration 1)
    hipMemsetAsync(m, 0, NR * 64 * sizeof(float) + 4096, stream);  // m + padded embed
    k_mp<<<NP / 4, 256, 0, stream>>>(pfeat_b, hidden, off, deg, csr_ab, m);
    k_update0<<<NR * 16 / 256, 256, 0, stream>>>(hidden, m);

    // MP iteration 1 (final: fused pooling, no hidden store)
    k_mp<<<NP / 4, 256, 0, stream>>>(pfeat_b, hidden, off, deg, csr_ab, m);
    k_update1<<<128, 256, 0, stream>>>(hidden, m, embed);

    // Head
    k_head<<<1, 64, 0, stream>>>(embed, w_h1, b_h1, w_h2, b_h2, w_out, b_out, out);
}

// Round 14
// 153.356 us; speedup vs baseline: 1.4954x; 1.0108x over previous
//
#include <hip/hip_runtime.h>

#define H_ 64
#define HD_ 32
#define NP 8192
#define NR 16384
#define NC 65536
#define EP 65536
#define NCLS 11

typedef unsigned short ushort_t;
typedef unsigned int uint_t;

__device__ inline uint_t packbf2(float lo, float hi) {
    uint_t a = __builtin_bit_cast(uint_t, lo);
    uint_t b = __builtin_bit_cast(uint_t, hi);
    a = (a + 0x7FFFu + ((a >> 16) & 1u)) >> 16;
    b = (b + 0x7FFFu + ((b >> 16) & 1u)) & 0xFFFF0000u;
    return a | b;
}

// ---------------- zero scratch (replaces hipMemsetAsync: fillBuffer cost ~42us each!) ----------------
// Grid 1024x256. Zeroes m (NR*64 floats), deg (NP ints, blocks 0-7), embed (1024 floats, block 8).
__global__ __launch_bounds__(256) void k_zero(float* __restrict__ m, int* __restrict__ deg,
                                              float* __restrict__ embed) {
    int i = blockIdx.x * 256 + threadIdx.x;
    ((float4*)m)[i] = make_float4(0.f, 0.f, 0.f, 0.f);
    if (blockIdx.x < 8) {
        ((int4*)deg)[blockIdx.x * 256 + threadIdx.x] = make_int4(0, 0, 0, 0);
    }
    if (blockIdx.x == 8) {
        ((float4*)embed)[threadIdx.x] = make_float4(0.f, 0.f, 0.f, 0.f);
    }
}

// ---------------- CSR build ----------------
__global__ void k_hist(const int* __restrict__ pass_src, int* __restrict__ deg) {
    int e = blockIdx.x * 256 + threadIdx.x;
    if (e < EP) atomicAdd(&deg[pass_src[e]], 1);
}

__global__ void k_scan(const int* __restrict__ deg, int* __restrict__ off, int* __restrict__ cursor) {
    __shared__ int sums[256];
    int t = threadIdx.x;
    int local[32];
    int s = 0;
#pragma unroll
    for (int i = 0; i < 32; i++) { local[i] = s; s += deg[t * 32 + i]; }
    sums[t] = s;
    __syncthreads();
    for (int ofs = 1; ofs < 256; ofs <<= 1) {
        int u = (t >= ofs) ? sums[t - ofs] : 0;
        __syncthreads();
        sums[t] += u;
        __syncthreads();
    }
    int base = sums[t] - s;
#pragma unroll
    for (int i = 0; i < 32; i++) {
        int v = base + local[i];
        off[t * 32 + i] = v;
        cursor[t * 32 + i] = v;
    }
}

__global__ void k_scatter(const int* __restrict__ pass_src, const int* __restrict__ pass_dst,
                          const int* __restrict__ out_src, const int* __restrict__ in_dst,
                          int* __restrict__ cursor, int* __restrict__ csr_ab) {
    int e = blockIdx.x * 256 + threadIdx.x;
    if (e < EP) {
        int p = pass_src[e];
        int c = pass_dst[e];
        int a = out_src[c];
        int b = in_dst[c];
        int pos = atomicAdd(&cursor[p], 1);
        csr_ab[pos] = (a << 14) | b;
    }
}

// ---------------- permute w_mp into GEMM-friendly, LDS-bank-friendly B' ----------------
__global__ void k_perm(const float* __restrict__ w_mp, const float* __restrict__ b_mp,
                       float* __restrict__ Bp, float* __restrict__ biasp) {
    int i = blockIdx.x * 256 + threadIdx.x;  // over 64*2048
    int k = i >> 11, cg = i & 2047;
    int blk = cg >> 7, c = cg & 127;
    int quad = c >> 2, r = c & 3;
    int j = (quad < 16) ? (quad * 8 + r) : ((quad - 16) * 8 + 4 + r);
    int jp = blk * 128 + j;       // logical j' = d*64+h
    int d = jp >> 6, h = jp & 63;
    Bp[i] = w_mp[k * 2048 + h * 32 + d];
    if (i < 2048) biasp[i] = b_mp[h * 32 + d];
}

// ---------------- FeatureGen: routers -> hidden ----------------
__global__ __launch_bounds__(256) void k_router(const float* __restrict__ op,
                                                const float* __restrict__ w_op, const float* __restrict__ b_op,
                                                const float* __restrict__ w_fr, const float* __restrict__ b_fr,
                                                float* __restrict__ hidden) {
    __shared__ float s_wop[4 * 64];
    __shared__ float s_wfr[64 * 64];
    __shared__ float s_bop[64], s_bfr[64];
    __shared__ float s_tmp[16 * 64];
    int t = threadIdx.x;
    if (t < 64) { s_bop[t] = b_op[t]; s_bfr[t] = b_fr[t]; }
    if (t < 256) s_wop[t] = w_op[t];
    for (int i = t; i < 4096; i += 256) s_wfr[i] = w_fr[i];
    __syncthreads();
    int r0 = blockIdx.x * 16;
    for (int idx = t; idx < 16 * 64; idx += 256) {
        int row = idx >> 6, i = idx & 63;
        const float* o = op + (size_t)(r0 + row) * 4;
        float v = s_bop[i] + o[0] * s_wop[i] + o[1] * s_wop[64 + i] + o[2] * s_wop[128 + i] + o[3] * s_wop[192 + i];
        s_tmp[idx] = fmaxf(v, 0.f);
    }
    __syncthreads();
    for (int idx = t; idx < 16 * 64; idx += 256) {
        int row = idx >> 6, j = idx & 63;
        float acc = s_bfr[j];
        const float* tm = s_tmp + row * 64;
#pragma unroll 16
        for (int i = 0; i < 64; i++) acc += tm[i] * s_wfr[i * 64 + j];
        hidden[(size_t)(r0 + row) * 64 + j] = acc;
    }
}

// ---------------- FeatureGen: packets -> packet_feat ----------------
__global__ __launch_bounds__(256) void k_packet(const float* __restrict__ freq, const float* __restrict__ flit,
                                                const float* __restrict__ w_freq, const float* __restrict__ b_freq,
                                                const float* __restrict__ w_flit, const float* __restrict__ b_flit,
                                                const float* __restrict__ w_fp, const float* __restrict__ b_fp,
                                                float* __restrict__ pf) {
    __shared__ float s_wfl[32 * 64];
    __shared__ float s_wfp[128 * 64];
    __shared__ float s_tmp[16 * 128];
    __shared__ float s_wfq[64], s_bfq[64], s_bfl[64], s_bfp[64];
    int t = threadIdx.x;
    if (t < 64) { s_wfq[t] = w_freq[t]; s_bfq[t] = b_freq[t]; s_bfl[t] = b_flit[t]; s_bfp[t] = b_fp[t]; }
    for (int i = t; i < 2048; i += 256) s_wfl[i] = w_flit[i];
    for (int i = t; i < 8192; i += 256) s_wfp[i] = w_fp[i];
    __syncthreads();
    int r0 = blockIdx.x * 16;
    for (int idx = t; idx < 16 * 128; idx += 256) {
        int row = idx >> 7, i = idx & 127;
        float v;
        if (i < 64) {
            v = s_bfq[i] + freq[r0 + row] * s_wfq[i];
        } else {
            int ii = i - 64;
            float acc = s_bfl[ii];
            const float* f = flit + (size_t)(r0 + row) * 32;
#pragma unroll 8
            for (int k = 0; k < 32; k++) acc += f[k] * s_wfl[k * 64 + ii];
            v = acc;
        }
        s_tmp[idx] = fmaxf(v, 0.f);
    }
    __syncthreads();
    for (int idx = t; idx < 16 * 64; idx += 256) {
        int row = idx >> 6, j = idx & 63;
        float acc = s_bfp[j];
        const float* tm = s_tmp + row * 128;
#pragma unroll 16
        for (int i = 0; i < 128; i++) acc += tm[i] * s_wfp[i * 64 + j];
        pf[(size_t)(r0 + row) * 64 + j] = acc;
    }
}

// ---------------- pfeat_b[p][j'] (bf16) = pf @ B' + bias' ----------------
__global__ __launch_bounds__(256) void k_pfeat(const float* __restrict__ pf, const float* __restrict__ Bp,
                                               const float* __restrict__ biasp, ushort_t* __restrict__ pfeat_b) {
    __shared__ float As[64 * 68];
    __shared__ float Bs[64 * 132];
    int t = threadIdx.x;
    int p0 = blockIdx.x * 64;
    int j0 = blockIdx.y * 128;
#pragma unroll
    for (int it = 0; it < 4; it++) {
        int idx4 = t + it * 256;
        int r = idx4 >> 4, kq = idx4 & 15;
        float4 v = *(const float4*)(pf + (size_t)(p0 + r) * 64 + kq * 4);
        *(float4*)(As + r * 68 + kq * 4) = v;
    }
#pragma unroll
    for (int it = 0; it < 8; it++) {
        int idx4 = t + it * 256;
        int k = idx4 >> 5, c4 = idx4 & 31;
        float4 v = *(const float4*)(Bp + (size_t)k * 2048 + j0 + c4 * 4);
        *(float4*)(Bs + k * 132 + c4 * 4) = v;
    }
    __syncthreads();
    int pg = t >> 4, jg = t & 15;
    float acc0[8] = {}, acc1[8] = {}, acc2[8] = {}, acc3[8] = {};
    const float* asr = As + (pg * 4) * 68;
#pragma unroll 4
    for (int k = 0; k < 64; k++) {
        float4 w0 = *(const float4*)(Bs + k * 132 + jg * 4);
        float4 w1 = *(const float4*)(Bs + k * 132 + 64 + jg * 4);
        float a0 = asr[k], a1 = asr[68 + k], a2 = asr[136 + k], a3 = asr[204 + k];
        acc0[0] = fmaf(a0, w0.x, acc0[0]); acc0[1] = fmaf(a0, w0.y, acc0[1]);
        acc0[2] = fmaf(a0, w0.z, acc0[2]); acc0[3] = fmaf(a0, w0.w, acc0[3]);
        acc0[4] = fmaf(a0, w1.x, acc0[4]); acc0[5] = fmaf(a0, w1.y, acc0[5]);
        acc0[6] = fmaf(a0, w1.z, acc0[6]); acc0[7] = fmaf(a0, w1.w, acc0[7]);
        acc1[0] = fmaf(a1, w0.x, acc1[0]); acc1[1] = fmaf(a1, w0.y, acc1[1]);
        acc1[2] = fmaf(a1, w0.z, acc1[2]); acc1[3] = fmaf(a1, w0.w, acc1[3]);
        acc1[4] = fmaf(a1, w1.x, acc1[4]); acc1[5] = fmaf(a1, w1.y, acc1[5]);
        acc1[6] = fmaf(a1, w1.z, acc1[6]); acc1[7] = fmaf(a1, w1.w, acc1[7]);
        acc2[0] = fmaf(a2, w0.x, acc2[0]); acc2[1] = fmaf(a2, w0.y, acc2[1]);
        acc2[2] = fmaf(a2, w0.z, acc2[2]); acc2[3] = fmaf(a2, w0.w, acc2[3]);
        acc2[4] = fmaf(a2, w1.x, acc2[4]); acc2[5] = fmaf(a2, w1.y, acc2[5]);
        acc2[6] = fmaf(a2, w1.z, acc2[6]); acc2[7] = fmaf(a2, w1.w, acc2[7]);
        acc3[0] = fmaf(a3, w0.x, acc3[0]); acc3[1] = fmaf(a3, w0.y, acc3[1]);
        acc3[2] = fmaf(a3, w0.z, acc3[2]); acc3[3] = fmaf(a3, w0.w, acc3[3]);
        acc3[4] = fmaf(a3, w1.x, acc3[4]); acc3[5] = fmaf(a3, w1.y, acc3[5]);
        acc3[6] = fmaf(a3, w1.z, acc3[6]); acc3[7] = fmaf(a3, w1.w, acc3[7]);
    }
    float4 bb0 = *(const float4*)(biasp + j0 + jg * 4);
    float4 bb1 = *(const float4*)(biasp + j0 + 64 + jg * 4);
#define STORE_PP(ACC, PP) do { \
        uint4 v; \
        v.x = packbf2(ACC[0] + bb0.x, ACC[1] + bb0.y); \
        v.y = packbf2(ACC[2] + bb0.z, ACC[3] + bb0.w); \
        v.z = packbf2(ACC[4] + bb1.x, ACC[5] + bb1.y); \
        v.w = packbf2(ACC[6] + bb1.z, ACC[7] + bb1.w); \
        *(uint4*)(pfeat_b + (size_t)(p0 + pg * 4 + (PP)) * 2048 + j0 + jg * 8) = v; \
    } while (0)
    STORE_PP(acc0, 0);
    STORE_PP(acc1, 1);
    STORE_PP(acc2, 2);
    STORE_PP(acc3, 3);
#undef STORE_PP
}

// ---------------- Message passing (LDS-staged, group-of-4 pipelined) ----------------
__global__ __launch_bounds__(256) void k_mp(const ushort_t* __restrict__ pfeat_b, const float* __restrict__ hidden,
                                            const int* __restrict__ off, const int* __restrict__ deg,
                                            const int* __restrict__ csr_ab, float* __restrict__ m) {
    __shared__ float lds[4][8][64];   // per-wave 8 rows x 64 floats (8KB total)
    int wv = threadIdx.x >> 6;
    int wid = __builtin_amdgcn_readfirstlane((blockIdx.x << 2) + wv);
    int lane = threadIdx.x & 63;
    int hi = lane >> 5, d = lane & 31;
    const uint4* pr = (const uint4*)(pfeat_b + (size_t)wid * 2048 + d * 64 + hi * 32);
    float preg[32];
#pragma unroll
    for (int q = 0; q < 4; q++) {
        uint4 u = pr[q];
        preg[q * 8 + 0] = __builtin_bit_cast(float, u.x << 16);
        preg[q * 8 + 1] = __builtin_bit_cast(float, u.x & 0xFFFF0000u);
        preg[q * 8 + 2] = __builtin_bit_cast(float, u.y << 16);
        preg[q * 8 + 3] = __builtin_bit_cast(float, u.y & 0xFFFF0000u);
        preg[q * 8 + 4] = __builtin_bit_cast(float, u.z << 16);
        preg[q * 8 + 5] = __builtin_bit_cast(float, u.z & 0xFFFF0000u);
        preg[q * 8 + 6] = __builtin_bit_cast(float, u.w << 16);
        preg[q * 8 + 7] = __builtin_bit_cast(float, u.w & 0xFFFF0000u);
    }
    int e0 = off[wid];
    int n = deg[wid];
    if (n <= 0) return;
    const float4* hb4 = (const float4*)hidden;

    int ridx = lane >> 3;      // 0..7: row slot = edge (ridx>>1), a/b = ridx&1
    int jj = ridx >> 1;
    int ab = ridx & 1;
    int qq = lane & 7;
    int elast = e0 + n - 1;

    float4 v0, v1;
    int pkj;
    {
        int ec = e0 + jj; if (ec > elast) ec = elast;
        pkj = csr_ab[ec];
        int row = ab ? (pkj & 16383) : (pkj >> 14);
        v0 = hb4[row * 16 + qq];
        v1 = hb4[row * 16 + 8 + qq];
    }
    int ngroups = (n + 3) >> 2;
    for (int g = 0; g < ngroups; ++g) {
        *(float4*)&lds[wv][ridx][qq * 4] = v0;
        *(float4*)&lds[wv][ridx][qq * 4 + 32] = v1;
        int pkcur = pkj;
        if (g + 1 < ngroups) {
            int ec = e0 + (g + 1) * 4 + jj; if (ec > elast) ec = elast;
            pkj = csr_ab[ec];
            int row = ab ? (pkj & 16383) : (pkj >> 14);
            v0 = hb4[row * 16 + qq];
            v1 = hb4[row * 16 + 8 + qq];
        }
        int i0 = g * 4;
#pragma unroll
        for (int j = 0; j < 4; ++j) {
            if (i0 + j < n) {
                int pke = __shfl(pkcur, 16 * j, 64);
                int a_ = pke >> 14, b_ = pke & 16383;
                const float* ha = &lds[wv][2 * j][hi * 32];
                const float* hb = &lds[wv][2 * j + 1][hi * 32];
                float vi0 = 0, vi1 = 0, vi2 = 0, vi3 = 0, vo0 = 0, vo1 = 0, vo2 = 0, vo3 = 0;
#pragma unroll
                for (int q = 0; q < 8; q++) {
                    float4 xa = *(const float4*)(ha + q * 4);
                    float4 xb = *(const float4*)(hb + q * 4);
                    vi0 = fmaf(preg[4 * q + 0], xa.x, vi0);
                    vi1 = fmaf(preg[4 * q + 1], xa.y, vi1);
                    vi2 = fmaf(preg[4 * q + 2], xa.z, vi2);
                    vi3 = fmaf(preg[4 * q + 3], xa.w, vi3);
                    vo0 = fmaf(preg[4 * q + 0], xb.x, vo0);
                    vo1 = fmaf(preg[4 * q + 1], xb.y, vo1);
                    vo2 = fmaf(preg[4 * q + 2], xb.z, vo2);
                    vo3 = fmaf(preg[4 * q + 3], xb.w, vo3);
                }
                float vin = (vi0 + vi1) + (vi2 + vi3);
                float vout = (vo0 + vo1) + (vo2 + vo3);
                vin += __shfl_xor(vin, 32);
                vout += __shfl_xor(vout, 32);
                if (hi == 0) atomicAdd(&m[(size_t)b_ * 64 + d], vin);
                else         atomicAdd(&m[(size_t)a_ * 64 + 32 + d], vout);
            }
        }
    }
}

// ---------------- update: hidden = relu(hidden + m) ----------------
__global__ __launch_bounds__(256) void k_update0(float* __restrict__ hidden, float* __restrict__ m) {
    int i = blockIdx.x * 256 + threadIdx.x;  // exactly NR*16 threads
    float4* h4 = (float4*)hidden;
    float4* m4 = (float4*)m;
    float4 hv = h4[i];
    float4 mv = m4[i];
    float4 v;
    v.x = fmaxf(hv.x + mv.x, 0.f);
    v.y = fmaxf(hv.y + mv.y, 0.f);
    v.z = fmaxf(hv.z + mv.z, 0.f);
    v.w = fmaxf(hv.w + mv.w, 0.f);
    h4[i] = v;
    m4[i] = make_float4(0.f, 0.f, 0.f, 0.f);
}

// Final: no hidden store; fused column-sum pooling into line-padded embed.
__global__ __launch_bounds__(256) void k_update1(const float* __restrict__ hidden, const float* __restrict__ m,
                                                 float* __restrict__ embed) {
    int t = threadIdx.x;
    int base = blockIdx.x * 256 + t;
    const float4* h4 = (const float4*)hidden;
    const float4* m4 = (const float4*)m;
    float col[4] = {0.f, 0.f, 0.f, 0.f};
    for (int i = base; i < NR * 16; i += 128 * 256) {
        float4 hv = h4[i];
        float4 mv = m4[i];
        col[0] += fmaxf(hv.x + mv.x, 0.f);
        col[1] += fmaxf(hv.y + mv.y, 0.f);
        col[2] += fmaxf(hv.z + mv.z, 0.f);
        col[3] += fmaxf(hv.w + mv.w, 0.f);
    }
#pragma unroll
    for (int k = 0; k < 4; k++) {
        col[k] += __shfl_xor(col[k], 16);
        col[k] += __shfl_xor(col[k], 32);
    }
    __shared__ float scol[4][64];
    int w = t >> 6, lane = t & 63;
    if (lane < 16) {
#pragma unroll
        for (int k = 0; k < 4; k++) scol[w][lane * 4 + k] = col[k];
    }
    __syncthreads();
    if (t < 64) {
        atomicAdd(&embed[t * 16], scol[0][t] + scol[1][t] + scol[2][t] + scol[3][t]);
    }
}

// ---------------- prediction head (embed is line-padded: stride 16 floats) ----------------
__global__ void k_head(const float* __restrict__ embed,
                       const float* __restrict__ w_h1, const float* __restrict__ b_h1,
                       const float* __restrict__ w_h2, const float* __restrict__ b_h2,
                       const float* __restrict__ w_out, const float* __restrict__ b_out,
                       float* __restrict__ out) {
    __shared__ float e1[64], e2[64];
    int t = threadIdx.x;
    float acc = b_h1[t];
#pragma unroll 16
    for (int k = 0; k < 64; k++) acc += embed[k * 16] * w_h1[k * 64 + t];
    e1[t] = fmaxf(acc, 0.f);
    __syncthreads();
    acc = b_h2[t];
#pragma unroll 16
    for (int k = 0; k < 64; k++) acc += e1[k] * w_h2[k * 64 + t];
    e2[t] = fmaxf(acc, 0.f);
    __syncthreads();
    if (t < NCLS) {
        acc = b_out[t];
#pragma unroll 16
        for (int k = 0; k < 64; k++) acc += e2[k] * w_out[k * NCLS + t];
        out[t] = acc;
    }
}

extern "C" void kernel_launch(void* const* d_in, const int* in_sizes, int n_in,
                              void* d_out, int out_size, void* d_ws, size_t ws_size,
                              hipStream_t stream) {
    const float* freq   = (const float*)d_in[0];
    const float* flit   = (const float*)d_in[1];
    const float* op     = (const float*)d_in[2];
    const int* out_src  = (const int*)d_in[4];
    const int* in_dst   = (const int*)d_in[7];
    const int* pass_src = (const int*)d_in[8];
    const int* pass_dst = (const int*)d_in[9];
    const float* w_freq = (const float*)d_in[10];
    const float* b_freq = (const float*)d_in[11];
    const float* w_flit = (const float*)d_in[12];
    const float* b_flit = (const float*)d_in[13];
    const float* w_op   = (const float*)d_in[14];
    const float* b_op   = (const float*)d_in[15];
    const float* w_fp   = (const float*)d_in[18];
    const float* b_fp   = (const float*)d_in[19];
    const float* w_fr   = (const float*)d_in[20];
    const float* b_fr   = (const float*)d_in[21];
    const float* w_mp   = (const float*)d_in[24];
    const float* b_mp   = (const float*)d_in[25];
    const float* w_h1   = (const float*)d_in[26];
    const float* b_h1   = (const float*)d_in[27];
    const float* w_h2   = (const float*)d_in[28];
    const float* b_h2   = (const float*)d_in[29];
    const float* w_out  = (const float*)d_in[30];
    const float* b_out  = (const float*)d_in[31];
    float* out = (float*)d_out;

    char* ws = (char*)d_ws;
    ushort_t* pfeat_b  = (ushort_t*)(ws);                  // 32 MB
    float* hidden      = (float*)(ws + 33554432);          // 4 MB
    float* m           = (float*)(ws + 37748736);          // 4 MB
    float* embed       = (float*)(ws + 41943040);          // 4 KB (padded: 64 x 16 floats)
    float* packet_feat = (float*)(ws + 41947136);          // 2 MB
    float* Bp          = (float*)(ws + 44044288);          // 512 KB
    float* biasp       = (float*)(ws + 44568576);          // 8 KB
    int*   deg         = (int*)  (ws + 44576768);          // 32 KB
    int*   off         = (int*)  (ws + 44609536);          // 32 KB
    int*   cursor      = (int*)  (ws + 44642304);          // 32 KB
    int*   csr_ab      = (int*)  (ws + 44675072);          // 256 KB

    // zero scratch (m + deg + embed) in ONE cheap kernel — no hipMemsetAsync
    k_zero<<<1024, 256, 0, stream>>>(m, deg, embed);

    // CSR build
    k_hist<<<EP / 256, 256, 0, stream>>>(pass_src, deg);
    k_scan<<<1, 256, 0, stream>>>(deg, off, cursor);
    k_scatter<<<EP / 256, 256, 0, stream>>>(pass_src, pass_dst, out_src, in_dst, cursor, csr_ab);

    // Weight permutation + features
    k_perm<<<512, 256, 0, stream>>>(w_mp, b_mp, Bp, biasp);
    k_packet<<<NP / 16, 256, 0, stream>>>(freq, flit, w_freq, b_freq, w_flit, b_flit, w_fp, b_fp, packet_feat);
    k_pfeat<<<dim3(NP / 64, 16), 256, 0, stream>>>(packet_feat, Bp, biasp, pfeat_b);
    k_router<<<NR / 16, 256, 0, stream>>>(op, w_op, b_op, w_fr, b_fr, hidden);

    // MP iteration 0 (k_update0 re-zeroes m for iteration 1)
    k_mp<<<NP / 4, 256, 0, stream>>>(pfeat_b, hidden, off, deg, csr_ab, m);
    k_update0<<<NR * 16 / 256, 256, 0, stream>>>(hidden, m);

    // MP iteration 1 (final: fused pooling, no hidden store)
    k_mp<<<NP / 4, 256, 0, stream>>>(pfeat_b, hidden, off, deg, csr_ab, m);
    k_update1<<<128, 256, 0, stream>>>(hidden, m, embed);

    // Head
    k_head<<<1, 64, 0, stream>>>(embed, w_h1, b_h1, w_h2, b_h2, w_out, b_out, out);
}